// Round 15
// baseline (409.446 us; speedup 1.0000x reference)
//
#include <hip/hip_runtime.h>
#include <hip/hip_cooperative_groups.h>

namespace cg = cooperative_groups;

typedef unsigned short u16;
typedef __bf16 bf8 __attribute__((ext_vector_type(8)));
typedef float f4 __attribute__((ext_vector_type(4)));

#define E_EDGES 32768
#define N_NODES 4096
// col layout of w (WNUM=6400): A[u<64][w<64] @0, B[u<64][w<16] @4096, C[u<16][w<16] @5120, D[u<16][w<64] @5376
// tile = 16 cols x 128 k = 4KB; group g covers tiles 4g..4g+3; A g<64, B 64..79, C 80..83, D 84..99
#define N0_CONST 0.1118033988749895f       // sqrt(1/80); also equals N1*INV_SQRT3
#define INV_SQRT3_CONST 0.5773502691896258f

__device__ __forceinline__ u16 f2bf(float f) {
    unsigned u = __float_as_uint(f);
    u += 0x7FFFu + ((u >> 16) & 1u);   // RNE
    return (u16)(u >> 16);
}

// ============================== fallback path (R13 VERBATIM) ==============================

__global__ __launch_bounds__(256) void k_prep(const float* __restrict__ W2, const float* __restrict__ W1,
                                              u16* __restrict__ w2s, u16* __restrict__ w1t,
                                              int* __restrict__ deg, float* __restrict__ outz) {
    int b = blockIdx.x;
    int tid = threadIdx.x;
    if (b < 400) {
        __shared__ float w2l[128][17];           // [k][c], +1 pad
        {
            int k = tid >> 1, c8 = (tid & 1) * 8;
            const float* src = W2 + (size_t)k * 6400 + b * 16 + c8;
            float tmpf[8];
#pragma unroll
            for (int j = 0; j < 8; j++) tmpf[j] = src[j];
#pragma unroll
            for (int j = 0; j < 8; j++) w2l[k][c8 + j] = tmpf[j];
        }
        __syncthreads();
        int ks = tid >> 6, l = tid & 63;
        int el = l & 15, q4 = l >> 4;
        u16 tmp[8];
#pragma unroll
        for (int j = 0; j < 8; j++)
            tmp[j] = f2bf(w2l[ks * 32 + q4 * 8 + j][el]);
        *(uint4*)(w2s + b * 2048 + ks * 512 + l * 8) = *(uint4*)tmp;
    } else if (b < 416) {
        int t = (b - 400) * 256 + tid;
#pragma unroll
        for (int i = 0; i < 4; i++) {
            int idx = t * 4 + i;                // idx = c*128 + k
            int c = idx >> 7, k = idx & 127;
            w1t[idx] = f2bf(W1[k * 128 + c]);
        }
    } else if (b == 416) {
        *(int4*)&deg[tid * 16] = (int4){0, 0, 0, 0};
        *(int4*)&deg[tid * 16 + 4] = (int4){0, 0, 0, 0};
        *(int4*)&deg[tid * 16 + 8] = (int4){0, 0, 0, 0};
        *(int4*)&deg[tid * 16 + 12] = (int4){0, 0, 0, 0};
    } else {
        float4 z = {0.f, 0.f, 0.f, 0.f};
        float* p = outz + ((size_t)(b - 417) * 256 + tid) * 32;
#pragma unroll
        for (int i = 0; i < 8; i++) *(float4*)(p + i * 4) = z;
    }
}

// Shared main body (R13 k_main VERBATIM, as a device function so coop + fallback share it)
__device__ __forceinline__ void main_body(int b, int tid,
                                          const u16* __restrict__ w2s,
                                          const u16* __restrict__ w1t,
                                          const float* __restrict__ b1,
                                          const float* __restrict__ ea,
                                          const float* __restrict__ b2,
                                          const float* __restrict__ node_attr,
                                          const int* __restrict__ edge_index,
                                          const float* __restrict__ edge_sh,
                                          int* __restrict__ deg,
                                          float* __restrict__ outsum) {
    __shared__ alignas(16) union {
        u16 h[64][136];                               // 17408 B (prologue: ea staging, then h; +8 pad)
        struct { float bcB[64][17]; float bcC[3][64][17]; } bc;   // 17408 B (B/C cross-wave sums)
    } ovl;
    __shared__ float sT[64][66];              // s[u][e]; epilogue: out0[e][c]
    __shared__ float vT[3][16][66];           // v[i][u][e]; epilogue: out1 flat [e*48+cr]
    __shared__ float pT[16][66];              // INV_SQRT3*(v.sh1)[u][e]
    __shared__ float sh0_s[64];
    __shared__ float sh1_s[3][64];
    __shared__ int dst_s[64];
    __shared__ int src_s[64];

    int e0 = b * 64;
    int lane = tid & 63, wave = tid >> 6;
    int el = lane & 15, q4 = lane >> 4;

    // A-fragment double buffer + per-tile bias; issued earliest for latency
    bf8 a0[4], a1[4];
    float4 bb0, bb1;
    auto loadA = [&](int i, bf8 (&a)[4], float4& bb) {
        int g = (i < 20) ? 64 + i : (i < 84 ? i - 20 : i);   // phase order B,C,A,D
        int pn = 4 * g + wave;
        const u16* gp = w2s + (size_t)pn * 2048 + lane * 8;
        a[0] = *(const bf8*)(gp);
        a[1] = *(const bf8*)(gp + 512);
        a[2] = *(const bf8*)(gp + 1024);
        a[3] = *(const bf8*)(gp + 1536);
        bb = *(const float4*)(b2 + pn * 16 + q4 * 4);
    };
    loadA(0, a0, bb0);   // prefetch first tile under the whole prologue

    // phase 1: edge meta (+ deg histogram)
    if (tid < 64) {
        int ge = e0 + tid;
        int s = edge_index[ge];
        src_s[tid] = s;
        atomicAdd(&deg[s], 1);
        dst_s[tid] = edge_index[E_EDGES + ge];
        float4 sh = *(const float4*)(edge_sh + (size_t)ge * 4);
        sh0_s[tid] = sh.x; sh1_s[0][tid] = sh.y; sh1_s[1][tid] = sh.z; sh1_s[2][tid] = sh.w;
    }
    __syncthreads();

    // phase 2: node features (transposed into LDS) + ea tile bf16 into ovl.h
    {
        int e = tid >> 2, q = tid & 3;
        int dst = dst_s[e];
        const float* xp = node_attr + (size_t)dst * 112;
#pragma unroll
        for (int i = 0; i < 4; i++) {
            float4 f = *(const float4*)(xp + q * 16 + i * 4);
            int u = q * 16 + i * 4;
            sT[u + 0][e] = f.x; sT[u + 1][e] = f.y; sT[u + 2][e] = f.z; sT[u + 3][e] = f.w;
        }
        float vv[12];
#pragma unroll
        for (int i = 0; i < 3; i++) {
            float4 f = *(const float4*)(xp + 64 + q * 12 + i * 4);
            vv[i * 4 + 0] = f.x; vv[i * 4 + 1] = f.y; vv[i * 4 + 2] = f.z; vv[i * 4 + 3] = f.w;
        }
        float s1x = sh1_s[0][e], s1y = sh1_s[1][e], s1z = sh1_s[2][e];
#pragma unroll
        for (int u = 0; u < 4; u++) {
            float xa = vv[u * 3 + 0], xb = vv[u * 3 + 1], xc = vv[u * 3 + 2];
            int uu = q * 4 + u;
            vT[0][uu][e] = xa; vT[1][uu][e] = xb; vT[2][uu][e] = xc;
            pT[uu][e] = INV_SQRT3_CONST * (xa * s1x + xb * s1y + xc * s1z);
        }
        // ea staging: 32 cols per thread, f32 -> bf16
        const float4* src = (const float4*)(ea + (size_t)(e0 + e) * 128 + q * 32);
#pragma unroll
        for (int i = 0; i < 8; i++) {
            float4 f = src[i];
            int c = q * 32 + i * 4;
            ovl.h[e][c + 0] = f2bf(f.x); ovl.h[e][c + 1] = f2bf(f.y);
            ovl.h[e][c + 2] = f2bf(f.z); ovl.h[e][c + 3] = f2bf(f.w);
        }
    }
    __syncthreads();

    // phase 3: h = relu(ea@W1+b1) — 16-MFMA block (ea read from ovl.h, stride 136)
    {
        f4 hacc[4][2];
#pragma unroll
        for (int m = 0; m < 4; m++)
#pragma unroll
            for (int nt = 0; nt < 2; nt++) hacc[m][nt] = (f4){0.f, 0.f, 0.f, 0.f};
#pragma unroll
        for (int ks = 0; ks < 4; ks++) {
            bf8 a[4], bb[2];
#pragma unroll
            for (int m = 0; m < 4; m++) a[m] = *(const bf8*)&ovl.h[m * 16 + el][ks * 32 + q4 * 8];
#pragma unroll
            for (int nt = 0; nt < 2; nt++) {
                int n = wave * 32 + nt * 16 + el;
                bb[nt] = *(const bf8*)(w1t + n * 128 + ks * 32 + q4 * 8);
            }
#pragma unroll
            for (int m = 0; m < 4; m++)
#pragma unroll
                for (int nt = 0; nt < 2; nt++)
                    hacc[m][nt] = __builtin_amdgcn_mfma_f32_16x16x32_bf16(a[m], bb[nt], hacc[m][nt], 0, 0, 0);
        }
        __syncthreads();   // all ea reads done -> safe to overwrite ovl.h with h
#pragma unroll
        for (int m = 0; m < 4; m++)
#pragma unroll
            for (int nt = 0; nt < 2; nt++) {
                int n = wave * 32 + nt * 16 + el;
                float bias = b1[n];
#pragma unroll
                for (int r = 0; r < 4; r++) {
                    int e = m * 16 + q4 * 4 + r;
                    ovl.h[e][n] = f2bf(fmaxf(hacc[m][nt][r] + bias, 0.f));
                }
            }
    }
    __syncthreads();

    // h B-fragments for ALL 4 edge-groups (64 VGPRs) + per-lane sh0 factors
    bf8 hbf[4][4];
#pragma unroll
    for (int nt = 0; nt < 4; nt++)
#pragma unroll
        for (int ks = 0; ks < 4; ks++)
            hbf[nt][ks] = *(const bf8*)&ovl.h[nt * 16 + el][ks * 32 + q4 * 8];
    float sh0n4[4];
#pragma unroll
    for (int nt = 0; nt < 4; nt++) sh0n4[nt] = sh0_s[nt * 16 + el];
    __syncthreads();   // everyone done reading ovl.h -> becomes bc scratch

    // zero bc scratch (17408B = 4352 floats)
    for (int idx = tid; idx < 4352; idx += 256) ((float*)&ovl.bc)[idx] = 0.f;
    __syncthreads();   // bc zeroed before any wave's atomics

    auto mfmaG = [&](const bf8 (&a)[4], const float4& bb, f4 (&wf)[4]) {
#pragma unroll
        for (int nt = 0; nt < 4; nt++) wf[nt] = (f4){bb.x, bb.y, bb.z, bb.w};
#pragma unroll
        for (int ks = 0; ks < 4; ks++)
#pragma unroll
            for (int nt = 0; nt < 4; nt++)
                wf[nt] = __builtin_amdgcn_mfma_f32_16x16x32_bf16(a[ks], hbf[nt][ks], wf[nt], 0, 0, 0);
    };
    // result layout per lane: wf[nt][r] = w[edge = nt*16+el][col-in-tile = q4*4+r]

#define STEP(INXT, ACUR, BBCUR, ANXT, BBNXT, CON) \
    { if ((INXT) < 100) loadA((INXT), ANXT, BBNXT); mfmaG(ACUR, BBCUR, wf); CON; }

    f4 wf[4];

    // ---- B phase (i=0..15, g=64+i, u=4*i+wave; out col w = q4*4+r)
    {
        f4 accBn[4];
#pragma unroll
        for (int nt = 0; nt < 4; nt++) accBn[nt] = (f4){0.f, 0.f, 0.f, 0.f};
        auto conB = [&](int ib) {
            int u = 4 * ib + wave;
#pragma unroll
            for (int nt = 0; nt < 4; nt++) {
                float f = sT[u][nt * 16 + el];
                accBn[nt] += f * wf[nt];
            }
        };
        for (int ii = 0; ii < 16; ii += 2) {
            STEP(ii + 1, a0, bb0, a1, bb1, conB(ii));
            STEP(ii + 2, a1, bb1, a0, bb0, conB(ii + 1));
        }
#pragma unroll
        for (int nt = 0; nt < 4; nt++)
#pragma unroll
            for (int r = 0; r < 4; r++)
                atomicAdd(&ovl.bc.bcB[nt * 16 + el][q4 * 4 + r], accBn[nt][r]);
    }

    // ---- C phase (i=16..19, g=80+(i-16), u=4*(i-16)+wave)
    {
        f4 accCn[3][4];
#pragma unroll
        for (int i3 = 0; i3 < 3; i3++)
#pragma unroll
            for (int nt = 0; nt < 4; nt++) accCn[i3][nt] = (f4){0.f, 0.f, 0.f, 0.f};
        auto conC = [&](int ic) {
            int u = 4 * ic + wave;
#pragma unroll
            for (int nt = 0; nt < 4; nt++) {
#pragma unroll
                for (int i3 = 0; i3 < 3; i3++) {
                    float f = vT[i3][u][nt * 16 + el];
                    accCn[i3][nt] += f * wf[nt];
                }
            }
        };
        for (int ii = 0; ii < 4; ii += 2) {
            STEP(16 + ii + 1, a0, bb0, a1, bb1, conC(ii));
            STEP(16 + ii + 2, a1, bb1, a0, bb0, conC(ii + 1));
        }
#pragma unroll
        for (int i3 = 0; i3 < 3; i3++)
#pragma unroll
            for (int nt = 0; nt < 4; nt++)
#pragma unroll
                for (int r = 0; r < 4; r++)
                    atomicAdd(&ovl.bc.bcC[i3][nt * 16 + el][q4 * 4 + r], accCn[i3][nt][r]);
    }

    // ---- A phase (i=20..83, g=i-20=u) then D phase (i=84..99, u=i-84); both -> acc0n
    f4 acc0n[4];
#pragma unroll
    for (int nt = 0; nt < 4; nt++) acc0n[nt] = (f4){0.f, 0.f, 0.f, 0.f};
    {
        auto conA = [&](int ia) {
#pragma unroll
            for (int nt = 0; nt < 4; nt++) {
                float f = sh0n4[nt] * sT[ia][nt * 16 + el];
                acc0n[nt] += f * wf[nt];
            }
        };
        for (int ii = 0; ii < 64; ii += 2) {
            STEP(20 + ii + 1, a0, bb0, a1, bb1, conA(ii));
            STEP(20 + ii + 2, a1, bb1, a0, bb0, conA(ii + 1));
        }
        auto conD = [&](int id_) {
#pragma unroll
            for (int nt = 0; nt < 4; nt++) {
                float f = pT[id_][nt * 16 + el];
                acc0n[nt] += f * wf[nt];
            }
        };
        for (int ii = 0; ii < 16; ii += 2) {
            STEP(84 + ii + 1, a0, bb0, a1, bb1, conD(ii));
            STEP(84 + ii + 2, a1, bb1, a0, bb0, conD(ii + 1));
        }
    }
#undef STEP

    __syncthreads();   // loop reads of sT/vT/pT done; all bc atomics landed

    // out0 -> sT[e][c]: wave owns col block wave*16 (A/D cols), all 64 edges
#pragma unroll
    for (int nt = 0; nt < 4; nt++)
#pragma unroll
        for (int r = 0; r < 4; r++)
            sT[nt * 16 + el][wave * 16 + q4 * 4 + r] = N0_CONST * acc0n[nt][r];
    // out1 assembly from bc sums -> vflat [e*48 + w*3 + i]
    {
        float* vflat = (float*)vT;
        for (int idx = tid; idx < 3072; idx += 256) {
            int e = idx / 48;
            int rem = idx - e * 48;
            int w = rem / 3;
            int i3 = rem - w * 3;
            vflat[idx] = N0_CONST * (ovl.bc.bcB[e][w] * sh1_s[i3][e] + ovl.bc.bcC[i3][e][w] * sh0_s[e]);
        }
    }
    __syncthreads();

    // ATOMIC scatter of the 64x112 tile into out[src*112 + c] (device-scope, L2-resident 1.8MB)
    {
        const float* vflat = (const float*)vT;
        for (int idx = tid; idx < 64 * 112; idx += 256) {
            int e = idx / 112;
            int c = idx - e * 112;
            float val = (c < 64) ? sT[e][c] : vflat[e * 48 + (c - 64)];
            atomicAdd(&outsum[(size_t)src_s[e] * 112 + c], val);
        }
    }
}

__global__ __launch_bounds__(256, 2) void k_main(const u16* __restrict__ w2s,
                                                 const u16* __restrict__ w1t,
                                                 const float* __restrict__ b1,
                                                 const float* __restrict__ ea,
                                                 const float* __restrict__ b2,
                                                 const float* __restrict__ node_attr,
                                                 const int* __restrict__ edge_index,
                                                 const float* __restrict__ edge_sh,
                                                 int* __restrict__ deg,
                                                 float* __restrict__ outsum) {
    main_body(blockIdx.x, threadIdx.x, w2s, w1t, b1, ea, b2, node_attr, edge_index, edge_sh, deg, outsum);
}

__global__ __launch_bounds__(128) void k_fin(const int* __restrict__ deg,
                                             const float* __restrict__ node_attr,
                                             float* __restrict__ out) {
    int n = blockIdx.x;
    int c = threadIdx.x;
    if (c >= 112) return;
    float d = fmaxf((float)deg[n], 1.f);
    out[n * 112 + c] = out[n * 112 + c] / d + node_attr[n * 112 + c];
}

// ============================== cooperative path (single launch) ==============================
// Phase P (prep+zero) -> fence+grid.sync -> Phase M (main_body) -> fence+grid.sync -> Phase F.
// Cross-XCD L2s are NOT coherent: __threadfence() (device-scope release) before EACH grid.sync
// so phase-P plain stores and phase-M scatters are visible to other XCDs (R14 lacked the first).
__global__ __launch_bounds__(256, 2) void k_all(const float* __restrict__ W2,
                                                const float* __restrict__ W1,
                                                const float* __restrict__ b1,
                                                const float* __restrict__ ea,
                                                const float* __restrict__ b2,
                                                const float* __restrict__ node_attr,
                                                const int* __restrict__ edge_index,
                                                const float* __restrict__ edge_sh,
                                                u16* __restrict__ w2s,
                                                u16* __restrict__ w1t,
                                                int* __restrict__ deg,
                                                float* __restrict__ outsum) {
    cg::grid_group grid = cg::this_grid();
    int tid = threadIdx.x;
    int b = blockIdx.x;

    // Phase P (R13 k_prep logic; own small LDS — block roles)
    if (b < 400) {
        __shared__ float w2l[128][17];
        {
            int k = tid >> 1, c8 = (tid & 1) * 8;
            const float* src = W2 + (size_t)k * 6400 + b * 16 + c8;
            float tmpf[8];
#pragma unroll
            for (int j = 0; j < 8; j++) tmpf[j] = src[j];
#pragma unroll
            for (int j = 0; j < 8; j++) w2l[k][c8 + j] = tmpf[j];
        }
        __syncthreads();
        int ks = tid >> 6, l = tid & 63;
        int el = l & 15, q4 = l >> 4;
        u16 tmp[8];
#pragma unroll
        for (int j = 0; j < 8; j++)
            tmp[j] = f2bf(w2l[ks * 32 + q4 * 8 + j][el]);
        *(uint4*)(w2s + b * 2048 + ks * 512 + l * 8) = *(uint4*)tmp;
        __syncthreads();
    } else if (b < 416) {
        int t = (b - 400) * 256 + tid;
#pragma unroll
        for (int i = 0; i < 4; i++) {
            int idx = t * 4 + i;
            int c = idx >> 7, k = idx & 127;
            w1t[idx] = f2bf(W1[k * 128 + c]);
        }
    } else if (b == 416) {
        *(int4*)&deg[tid * 16] = (int4){0, 0, 0, 0};
        *(int4*)&deg[tid * 16 + 4] = (int4){0, 0, 0, 0};
        *(int4*)&deg[tid * 16 + 8] = (int4){0, 0, 0, 0};
        *(int4*)&deg[tid * 16 + 12] = (int4){0, 0, 0, 0};
    } else if (b < 473) {
        float4 z = {0.f, 0.f, 0.f, 0.f};
        float* p = outsum + ((size_t)(b - 417) * 256 + tid) * 32;
#pragma unroll
        for (int i = 0; i < 8; i++) *(float4*)(p + i * 4) = z;
    }
    __threadfence();
    grid.sync();

    // Phase M
    main_body(b, tid, w2s, w1t, b1, ea, b2, node_attr, edge_index, edge_sh, deg, outsum);

    // Phase F
    __threadfence();
    grid.sync();
    {
        int gtid = b * 256 + tid;
        for (int idx = gtid; idx < N_NODES * 112; idx += 512 * 256) {
            int n = idx / 112;
            float d = fmaxf((float)deg[n], 1.f);
            outsum[idx] = outsum[idx] / d + node_attr[idx];
        }
    }
}

extern "C" void kernel_launch(void* const* d_in, const int* in_sizes, int n_in,
                              void* d_out, int out_size, void* d_ws, size_t ws_size,
                              hipStream_t stream) {
    const float* node_attr  = (const float*)d_in[0];
    const int*   edge_index = (const int*)d_in[1];
    const float* edge_attr  = (const float*)d_in[2];
    const float* edge_sh    = (const float*)d_in[3];
    const float* W1         = (const float*)d_in[6];
    const float* b1         = (const float*)d_in[7];
    const float* W2         = (const float*)d_in[8];
    const float* b2         = (const float*)d_in[9];
    float* out = (float*)d_out;

    char* ws = (char*)d_ws;
    u16*   w2s    = (u16*)ws;                     // 6400*128*2  = 1,638,400
    u16*   w1t    = (u16*)(ws + 1638400);         // 128*128*2   =    32,768
    int*   deg    = (int*)(ws + 1671168);         // 4096*4

    void* args[] = {(void*)&W2, (void*)&W1, (void*)&b1, (void*)&edge_attr, (void*)&b2,
                    (void*)&node_attr, (void*)&edge_index, (void*)&edge_sh,
                    (void*)&w2s, (void*)&w1t, (void*)&deg, (void*)&out};
    hipError_t err = hipLaunchCooperativeKernel((void*)k_all, dim3(512), dim3(256), args, 0, stream);
    if (err != hipSuccess) {
        (void)hipGetLastError();   // clear error state; fall back to 3-launch pipeline (R13)
        k_prep<<<473, 256, 0, stream>>>(W2, W1, w2s, w1t, deg, out);
        k_main<<<512, 256, 0, stream>>>(w2s, w1t, b1, edge_attr, b2, node_attr, edge_index, edge_sh, deg, out);
        k_fin<<<4096, 128, 0, stream>>>(deg, node_attr, out);
    }
}

// Round 16
// 329.822 us; speedup vs baseline: 1.2414x; 1.2414x over previous
//
#include <hip/hip_runtime.h>

typedef unsigned short u16;
typedef __bf16 bf8 __attribute__((ext_vector_type(8)));
typedef float f4 __attribute__((ext_vector_type(4)));

#define E_EDGES 32768
#define N_NODES 4096
// col layout of w (WNUM=6400): A[u<64][w<64] @0, B[u<64][w<16] @4096, C[u<16][w<16] @5120, D[u<16][w<64] @5376
// tile = 16 cols x 128 k = 4KB; group g covers tiles 4g..4g+3; A g<64, B 64..79, C 80..83, D 84..99
#define N0_CONST 0.1118033988749895f       // sqrt(1/80); also equals N1*INV_SQRT3
#define INV_SQRT3_CONST 0.5773502691896258f

__device__ __forceinline__ u16 f2bf(float f) {
    unsigned u = __float_as_uint(f);
    u += 0x7FFFu + ((u >> 16) & 1u);   // RNE
    return (u16)(u >> 16);
}

// Weight prep + zero-fill (R13 verbatim + bar zero):
//  blocks 0..399:   w2s fragment-order swizzle; 400..415: w1t; 416: zero deg+bar;
//  417..472: zero out
__global__ __launch_bounds__(256) void k_prep(const float* __restrict__ W2, const float* __restrict__ W1,
                                              u16* __restrict__ w2s, u16* __restrict__ w1t,
                                              int* __restrict__ deg, int* __restrict__ bar,
                                              float* __restrict__ outz) {
    int b = blockIdx.x;
    int tid = threadIdx.x;
    if (b < 400) {
        __shared__ float w2l[128][17];           // [k][c], +1 pad
        {
            int k = tid >> 1, c8 = (tid & 1) * 8;
            const float* src = W2 + (size_t)k * 6400 + b * 16 + c8;
            float tmpf[8];
#pragma unroll
            for (int j = 0; j < 8; j++) tmpf[j] = src[j];
#pragma unroll
            for (int j = 0; j < 8; j++) w2l[k][c8 + j] = tmpf[j];
        }
        __syncthreads();
        int ks = tid >> 6, l = tid & 63;
        int el = l & 15, q4 = l >> 4;
        u16 tmp[8];
#pragma unroll
        for (int j = 0; j < 8; j++)
            tmp[j] = f2bf(w2l[ks * 32 + q4 * 8 + j][el]);
        *(uint4*)(w2s + b * 2048 + ks * 512 + l * 8) = *(uint4*)tmp;
    } else if (b < 416) {
        int t = (b - 400) * 256 + tid;
#pragma unroll
        for (int i = 0; i < 4; i++) {
            int idx = t * 4 + i;                // idx = c*128 + k
            int c = idx >> 7, k = idx & 127;
            w1t[idx] = f2bf(W1[k * 128 + c]);
        }
    } else if (b == 416) {
        *(int4*)&deg[tid * 16] = (int4){0, 0, 0, 0};
        *(int4*)&deg[tid * 16 + 4] = (int4){0, 0, 0, 0};
        *(int4*)&deg[tid * 16 + 8] = (int4){0, 0, 0, 0};
        *(int4*)&deg[tid * 16 + 12] = (int4){0, 0, 0, 0};
        if (tid == 0) *bar = 0;
    } else {
        float4 z = {0.f, 0.f, 0.f, 0.f};
        float* p = outz + ((size_t)(b - 417) * 256 + tid) * 32;
#pragma unroll
        for (int i = 0; i < 8; i++) *(float4*)(p + i * 4) = z;
    }
}

// Fused: h -> w -> contraction -> atomic scatter -> SOFTWARE GRID BARRIER -> finalize.
// Loop/epilogue = R13 VERBATIM. ROUND-16: k_fin fused behind a hand-rolled device-scope
// atomic barrier. Deadlock-free: grid 512 = EXACTLY 2 blocks/CU x 256 CU co-residency
// (launch_bounds(256,2), VGPR 100<=128, LDS 52.7KB) -> all blocks resident. Coop launch
// (R15) did the same fusion correctly but 3x slower; this replaces grid.sync with one
// atomicAdd + L2 spin (~us).
__global__ __launch_bounds__(256, 2) void k_main(const u16* __restrict__ w2s,
                                                 const u16* __restrict__ w1t,
                                                 const float* __restrict__ b1,
                                                 const float* __restrict__ ea,
                                                 const float* __restrict__ b2,
                                                 const float* __restrict__ node_attr,
                                                 const int* __restrict__ edge_index,
                                                 const float* __restrict__ edge_sh,
                                                 int* __restrict__ deg,
                                                 int* __restrict__ bar,
                                                 float* __restrict__ outsum) {
    __shared__ alignas(16) union {
        u16 h[64][136];                               // 17408 B (prologue: ea staging, then h; +8 pad)
        struct { float bcB[64][17]; float bcC[3][64][17]; } bc;   // 17408 B (B/C cross-wave sums)
    } ovl;
    __shared__ float sT[64][66];              // s[u][e]; epilogue: out0[e][c]
    __shared__ float vT[3][16][66];           // v[i][u][e]; epilogue: out1 flat [e*48+cr]
    __shared__ float pT[16][66];              // INV_SQRT3*(v.sh1)[u][e]
    __shared__ float sh0_s[64];
    __shared__ float sh1_s[3][64];
    __shared__ int dst_s[64];
    __shared__ int src_s[64];

    int tid = threadIdx.x;
    int b = blockIdx.x;
    int e0 = b * 64;
    int lane = tid & 63, wave = tid >> 6;
    int el = lane & 15, q4 = lane >> 4;

    // A-fragment double buffer + per-tile bias; issued earliest for latency
    bf8 a0[4], a1[4];
    float4 bb0, bb1;
    auto loadA = [&](int i, bf8 (&a)[4], float4& bb) {
        int g = (i < 20) ? 64 + i : (i < 84 ? i - 20 : i);   // phase order B,C,A,D
        int pn = 4 * g + wave;
        const u16* gp = w2s + (size_t)pn * 2048 + lane * 8;
        a[0] = *(const bf8*)(gp);
        a[1] = *(const bf8*)(gp + 512);
        a[2] = *(const bf8*)(gp + 1024);
        a[3] = *(const bf8*)(gp + 1536);
        bb = *(const float4*)(b2 + pn * 16 + q4 * 4);
    };
    loadA(0, a0, bb0);   // prefetch first tile under the whole prologue

    // phase 1: edge meta (+ deg histogram)
    if (tid < 64) {
        int ge = e0 + tid;
        int s = edge_index[ge];
        src_s[tid] = s;
        atomicAdd(&deg[s], 1);
        dst_s[tid] = edge_index[E_EDGES + ge];
        float4 sh = *(const float4*)(edge_sh + (size_t)ge * 4);
        sh0_s[tid] = sh.x; sh1_s[0][tid] = sh.y; sh1_s[1][tid] = sh.z; sh1_s[2][tid] = sh.w;
    }
    __syncthreads();

    // phase 2: node features (transposed into LDS) + ea tile bf16 into ovl.h
    {
        int e = tid >> 2, q = tid & 3;
        int dst = dst_s[e];
        const float* xp = node_attr + (size_t)dst * 112;
#pragma unroll
        for (int i = 0; i < 4; i++) {
            float4 f = *(const float4*)(xp + q * 16 + i * 4);
            int u = q * 16 + i * 4;
            sT[u + 0][e] = f.x; sT[u + 1][e] = f.y; sT[u + 2][e] = f.z; sT[u + 3][e] = f.w;
        }
        float vv[12];
#pragma unroll
        for (int i = 0; i < 3; i++) {
            float4 f = *(const float4*)(xp + 64 + q * 12 + i * 4);
            vv[i * 4 + 0] = f.x; vv[i * 4 + 1] = f.y; vv[i * 4 + 2] = f.z; vv[i * 4 + 3] = f.w;
        }
        float s1x = sh1_s[0][e], s1y = sh1_s[1][e], s1z = sh1_s[2][e];
#pragma unroll
        for (int u = 0; u < 4; u++) {
            float xa = vv[u * 3 + 0], xb = vv[u * 3 + 1], xc = vv[u * 3 + 2];
            int uu = q * 4 + u;
            vT[0][uu][e] = xa; vT[1][uu][e] = xb; vT[2][uu][e] = xc;
            pT[uu][e] = INV_SQRT3_CONST * (xa * s1x + xb * s1y + xc * s1z);
        }
        // ea staging: 32 cols per thread, f32 -> bf16
        const float4* src = (const float4*)(ea + (size_t)(e0 + e) * 128 + q * 32);
#pragma unroll
        for (int i = 0; i < 8; i++) {
            float4 f = src[i];
            int c = q * 32 + i * 4;
            ovl.h[e][c + 0] = f2bf(f.x); ovl.h[e][c + 1] = f2bf(f.y);
            ovl.h[e][c + 2] = f2bf(f.z); ovl.h[e][c + 3] = f2bf(f.w);
        }
    }
    __syncthreads();

    // phase 3: h = relu(ea@W1+b1) — 16-MFMA block (ea read from ovl.h, stride 136)
    {
        f4 hacc[4][2];
#pragma unroll
        for (int m = 0; m < 4; m++)
#pragma unroll
            for (int nt = 0; nt < 2; nt++) hacc[m][nt] = (f4){0.f, 0.f, 0.f, 0.f};
#pragma unroll
        for (int ks = 0; ks < 4; ks++) {
            bf8 a[4], bb[2];
#pragma unroll
            for (int m = 0; m < 4; m++) a[m] = *(const bf8*)&ovl.h[m * 16 + el][ks * 32 + q4 * 8];
#pragma unroll
            for (int nt = 0; nt < 2; nt++) {
                int n = wave * 32 + nt * 16 + el;
                bb[nt] = *(const bf8*)(w1t + n * 128 + ks * 32 + q4 * 8);
            }
#pragma unroll
            for (int m = 0; m < 4; m++)
#pragma unroll
                for (int nt = 0; nt < 2; nt++)
                    hacc[m][nt] = __builtin_amdgcn_mfma_f32_16x16x32_bf16(a[m], bb[nt], hacc[m][nt], 0, 0, 0);
        }
        __syncthreads();   // all ea reads done -> safe to overwrite ovl.h with h
#pragma unroll
        for (int m = 0; m < 4; m++)
#pragma unroll
            for (int nt = 0; nt < 2; nt++) {
                int n = wave * 32 + nt * 16 + el;
                float bias = b1[n];
#pragma unroll
                for (int r = 0; r < 4; r++) {
                    int e = m * 16 + q4 * 4 + r;
                    ovl.h[e][n] = f2bf(fmaxf(hacc[m][nt][r] + bias, 0.f));
                }
            }
    }
    __syncthreads();

    // h B-fragments for ALL 4 edge-groups (64 VGPRs) + per-lane sh0 factors
    bf8 hbf[4][4];
#pragma unroll
    for (int nt = 0; nt < 4; nt++)
#pragma unroll
        for (int ks = 0; ks < 4; ks++)
            hbf[nt][ks] = *(const bf8*)&ovl.h[nt * 16 + el][ks * 32 + q4 * 8];
    float sh0n4[4];
#pragma unroll
    for (int nt = 0; nt < 4; nt++) sh0n4[nt] = sh0_s[nt * 16 + el];
    __syncthreads();   // everyone done reading ovl.h -> becomes bc scratch

    // zero bc scratch (17408B = 4352 floats)
    for (int idx = tid; idx < 4352; idx += 256) ((float*)&ovl.bc)[idx] = 0.f;
    __syncthreads();   // bc zeroed before any wave's atomics

    auto mfmaG = [&](const bf8 (&a)[4], const float4& bb, f4 (&wf)[4]) {
#pragma unroll
        for (int nt = 0; nt < 4; nt++) wf[nt] = (f4){bb.x, bb.y, bb.z, bb.w};
#pragma unroll
        for (int ks = 0; ks < 4; ks++)
#pragma unroll
            for (int nt = 0; nt < 4; nt++)
                wf[nt] = __builtin_amdgcn_mfma_f32_16x16x32_bf16(a[ks], hbf[nt][ks], wf[nt], 0, 0, 0);
    };
    // result layout per lane: wf[nt][r] = w[edge = nt*16+el][col-in-tile = q4*4+r]

#define STEP(INXT, ACUR, BBCUR, ANXT, BBNXT, CON) \
    { if ((INXT) < 100) loadA((INXT), ANXT, BBNXT); mfmaG(ACUR, BBCUR, wf); CON; }

    f4 wf[4];

    // ---- B phase (i=0..15, g=64+i, u=4*i+wave; out col w = q4*4+r)
    {
        f4 accBn[4];
#pragma unroll
        for (int nt = 0; nt < 4; nt++) accBn[nt] = (f4){0.f, 0.f, 0.f, 0.f};
        auto conB = [&](int ib) {
            int u = 4 * ib + wave;
#pragma unroll
            for (int nt = 0; nt < 4; nt++) {
                float f = sT[u][nt * 16 + el];
                accBn[nt] += f * wf[nt];
            }
        };
        for (int ii = 0; ii < 16; ii += 2) {
            STEP(ii + 1, a0, bb0, a1, bb1, conB(ii));
            STEP(ii + 2, a1, bb1, a0, bb0, conB(ii + 1));
        }
#pragma unroll
        for (int nt = 0; nt < 4; nt++)
#pragma unroll
            for (int r = 0; r < 4; r++)
                atomicAdd(&ovl.bc.bcB[nt * 16 + el][q4 * 4 + r], accBn[nt][r]);
    }

    // ---- C phase (i=16..19, g=80+(i-16), u=4*(i-16)+wave)
    {
        f4 accCn[3][4];
#pragma unroll
        for (int i3 = 0; i3 < 3; i3++)
#pragma unroll
            for (int nt = 0; nt < 4; nt++) accCn[i3][nt] = (f4){0.f, 0.f, 0.f, 0.f};
        auto conC = [&](int ic) {
            int u = 4 * ic + wave;
#pragma unroll
            for (int nt = 0; nt < 4; nt++) {
#pragma unroll
                for (int i3 = 0; i3 < 3; i3++) {
                    float f = vT[i3][u][nt * 16 + el];
                    accCn[i3][nt] += f * wf[nt];
                }
            }
        };
        for (int ii = 0; ii < 4; ii += 2) {
            STEP(16 + ii + 1, a0, bb0, a1, bb1, conC(ii));
            STEP(16 + ii + 2, a1, bb1, a0, bb0, conC(ii + 1));
        }
#pragma unroll
        for (int i3 = 0; i3 < 3; i3++)
#pragma unroll
            for (int nt = 0; nt < 4; nt++)
#pragma unroll
                for (int r = 0; r < 4; r++)
                    atomicAdd(&ovl.bc.bcC[i3][nt * 16 + el][q4 * 4 + r], accCn[i3][nt][r]);
    }

    // ---- A phase (i=20..83, g=i-20=u) then D phase (i=84..99, u=i-84); both -> acc0n
    f4 acc0n[4];
#pragma unroll
    for (int nt = 0; nt < 4; nt++) acc0n[nt] = (f4){0.f, 0.f, 0.f, 0.f};
    {
        auto conA = [&](int ia) {
#pragma unroll
            for (int nt = 0; nt < 4; nt++) {
                float f = sh0n4[nt] * sT[ia][nt * 16 + el];
                acc0n[nt] += f * wf[nt];
            }
        };
        for (int ii = 0; ii < 64; ii += 2) {
            STEP(20 + ii + 1, a0, bb0, a1, bb1, conA(ii));
            STEP(20 + ii + 2, a1, bb1, a0, bb0, conA(ii + 1));
        }
        auto conD = [&](int id_) {
#pragma unroll
            for (int nt = 0; nt < 4; nt++) {
                float f = pT[id_][nt * 16 + el];
                acc0n[nt] += f * wf[nt];
            }
        };
        for (int ii = 0; ii < 16; ii += 2) {
            STEP(84 + ii + 1, a0, bb0, a1, bb1, conD(ii));
            STEP(84 + ii + 2, a1, bb1, a0, bb0, conD(ii + 1));
        }
    }
#undef STEP

    __syncthreads();   // loop reads of sT/vT/pT done; all bc atomics landed

    // out0 -> sT[e][c]: wave owns col block wave*16 (A/D cols), all 64 edges
#pragma unroll
    for (int nt = 0; nt < 4; nt++)
#pragma unroll
        for (int r = 0; r < 4; r++)
            sT[nt * 16 + el][wave * 16 + q4 * 4 + r] = N0_CONST * acc0n[nt][r];
    // out1 assembly from bc sums -> vflat [e*48 + w*3 + i]
    {
        float* vflat = (float*)vT;
        for (int idx = tid; idx < 3072; idx += 256) {
            int e = idx / 48;
            int rem = idx - e * 48;
            int w = rem / 3;
            int i3 = rem - w * 3;
            vflat[idx] = N0_CONST * (ovl.bc.bcB[e][w] * sh1_s[i3][e] + ovl.bc.bcC[i3][e][w] * sh0_s[e]);
        }
    }
    __syncthreads();

    // ATOMIC scatter of the 64x112 tile into out[src*112 + c] (device-scope, L2-resident 1.8MB)
    {
        const float* vflat = (const float*)vT;
        for (int idx = tid; idx < 64 * 112; idx += 256) {
            int e = idx / 112;
            int c = idx - e * 112;
            float val = (c < 64) ? sT[e][c] : vflat[e * 48 + (c - 64)];
            atomicAdd(&outsum[(size_t)src_s[e] * 112 + c], val);
        }
    }

    // ---- software grid barrier (all 512 blocks co-resident by construction) ----
    __threadfence();       // release: scatters + deg atomics visible device-wide
    __syncthreads();       // all threads of this block done before signaling
    if (tid == 0) {
        atomicAdd(bar, 1);
        while (__hip_atomic_load(bar, __ATOMIC_ACQUIRE, __HIP_MEMORY_SCOPE_AGENT) < 512) {}
    }
    __syncthreads();       // fan the release out to all threads
    __threadfence();       // acquire

    // ---- finalize (was k_fin): out = out/deg + node_attr, grid-strided ----
    {
        int gtid = b * 256 + tid;
        for (int idx = gtid; idx < N_NODES * 112; idx += 512 * 256) {
            int n = idx / 112;
            float d = fmaxf((float)deg[n], 1.f);
            outsum[idx] = outsum[idx] / d + node_attr[idx];
        }
    }
}

extern "C" void kernel_launch(void* const* d_in, const int* in_sizes, int n_in,
                              void* d_out, int out_size, void* d_ws, size_t ws_size,
                              hipStream_t stream) {
    const float* node_attr  = (const float*)d_in[0];
    const int*   edge_index = (const int*)d_in[1];
    const float* edge_attr  = (const float*)d_in[2];
    const float* edge_sh    = (const float*)d_in[3];
    const float* W1         = (const float*)d_in[6];
    const float* b1         = (const float*)d_in[7];
    const float* W2         = (const float*)d_in[8];
    const float* b2         = (const float*)d_in[9];
    float* out = (float*)d_out;

    char* ws = (char*)d_ws;
    u16*   w2s    = (u16*)ws;                     // 6400*128*2  = 1,638,400
    u16*   w1t    = (u16*)(ws + 1638400);         // 128*128*2   =    32,768
    int*   deg    = (int*)(ws + 1671168);         // 4096*4
    int*   bar    = (int*)(ws + 1687552);         // 4

    k_prep<<<473, 256, 0, stream>>>(W2, W1, w2s, w1t, deg, bar, out);
    k_main<<<512, 256, 0, stream>>>(w2s, w1t, b1, edge_attr, b2, node_attr, edge_index, edge_sh, deg, bar, out);
}

// Round 17
// 181.764 us; speedup vs baseline: 2.2526x; 1.8146x over previous
//
#include <hip/hip_runtime.h>

typedef unsigned short u16;
typedef __bf16 bf8 __attribute__((ext_vector_type(8)));
typedef float f4 __attribute__((ext_vector_type(4)));

#define E_EDGES 32768
#define N_NODES 4096
// col layout of w (WNUM=6400): A[u<64][w<64] @0, B[u<64][w<16] @4096, C[u<16][w<16] @5120, D[u<16][w<64] @5376
// tile = 16 cols x 128 k = 4KB; group g covers tiles 4g..4g+3; A g<64, B 64..79, C 80..83, D 84..99
#define N0_CONST 0.1118033988749895f       // sqrt(1/80); also equals N1*INV_SQRT3
#define INV_SQRT3_CONST 0.5773502691896258f

__device__ __forceinline__ u16 f2bf(float f) {
    unsigned u = __float_as_uint(f);
    u += 0x7FFFu + ((u >> 16) & 1u);   // RNE
    return (u16)(u >> 16);
}

// Weight prep + zero-fill (R13 logic, deg-zero folded into the zero range):
//  blocks 0..399:   w2s fragment-order swizzle (LDS re-stage, 32B-contiguous W2 reads)
//  blocks 400..415: w1t[c*128+k] = bf16(W1[k*128+c])
//  blocks 416..455: zero out[458752] floats (40 blocks x 256 x ~45) -- grid-stride
//  block  456:      zero deg[4096]
__global__ __launch_bounds__(256) void k_prep(const float* __restrict__ W2, const float* __restrict__ W1,
                                              u16* __restrict__ w2s, u16* __restrict__ w1t,
                                              int* __restrict__ deg, float* __restrict__ outz) {
    int b = blockIdx.x;
    int tid = threadIdx.x;
    if (b < 400) {
        __shared__ float w2l[128][17];           // [k][c], +1 pad
        {
            int k = tid >> 1, c8 = (tid & 1) * 8;
            const float* src = W2 + (size_t)k * 6400 + b * 16 + c8;
            float tmpf[8];
#pragma unroll
            for (int j = 0; j < 8; j++) tmpf[j] = src[j];
#pragma unroll
            for (int j = 0; j < 8; j++) w2l[k][c8 + j] = tmpf[j];
        }
        __syncthreads();
        int ks = tid >> 6, l = tid & 63;
        int el = l & 15, q4 = l >> 4;
        u16 tmp[8];
#pragma unroll
        for (int j = 0; j < 8; j++)
            tmp[j] = f2bf(w2l[ks * 32 + q4 * 8 + j][el]);
        *(uint4*)(w2s + b * 2048 + ks * 512 + l * 8) = *(uint4*)tmp;
    } else if (b < 416) {
        int t = (b - 400) * 256 + tid;
#pragma unroll
        for (int i = 0; i < 4; i++) {
            int idx = t * 4 + i;                // idx = c*128 + k
            int c = idx >> 7, k = idx & 127;
            w1t[idx] = f2bf(W1[k * 128 + c]);
        }
    } else if (b < 456) {
        // zero out: 458752 floats = 114688 float4; 40 blocks x 256 threads grid-stride
        float4 z = {0.f, 0.f, 0.f, 0.f};
        for (int i4 = (b - 416) * 256 + tid; i4 < 114688; i4 += 40 * 256)
            *(float4*)(outz + (size_t)i4 * 4) = z;
    } else {
        *(int4*)&deg[tid * 16] = (int4){0, 0, 0, 0};
        *(int4*)&deg[tid * 16 + 4] = (int4){0, 0, 0, 0};
        *(int4*)&deg[tid * 16 + 8] = (int4){0, 0, 0, 0};
        *(int4*)&deg[tid * 16 + 12] = (int4){0, 0, 0, 0};
    }
}

// Fused: h = relu(ea@W1+b1) in-prologue -> w = h@W2+b2 tile-by-tile -> contraction
// -> ATOMIC scatter to out[src] (+ deg histogram). R13 VERBATIM (best verified: 107us).
__global__ __launch_bounds__(256, 2) void k_main(const u16* __restrict__ w2s,
                                                 const u16* __restrict__ w1t,
                                                 const float* __restrict__ b1,
                                                 const float* __restrict__ ea,
                                                 const float* __restrict__ b2,
                                                 const float* __restrict__ node_attr,
                                                 const int* __restrict__ edge_index,
                                                 const float* __restrict__ edge_sh,
                                                 int* __restrict__ deg,
                                                 float* __restrict__ outsum) {
    __shared__ alignas(16) union {
        u16 h[64][136];                               // 17408 B (prologue: ea staging, then h; +8 pad)
        struct { float bcB[64][17]; float bcC[3][64][17]; } bc;   // 17408 B (B/C cross-wave sums)
    } ovl;
    __shared__ float sT[64][66];              // s[u][e]; epilogue: out0[e][c]
    __shared__ float vT[3][16][66];           // v[i][u][e]; epilogue: out1 flat [e*48+cr]
    __shared__ float pT[16][66];              // INV_SQRT3*(v.sh1)[u][e]
    __shared__ float sh0_s[64];
    __shared__ float sh1_s[3][64];
    __shared__ int dst_s[64];
    __shared__ int src_s[64];

    int tid = threadIdx.x;
    int e0 = blockIdx.x * 64;
    int lane = tid & 63, wave = tid >> 6;
    int el = lane & 15, q4 = lane >> 4;

    // A-fragment double buffer + per-tile bias; issued earliest for latency
    bf8 a0[4], a1[4];
    float4 bb0, bb1;
    auto loadA = [&](int i, bf8 (&a)[4], float4& bb) {
        int g = (i < 20) ? 64 + i : (i < 84 ? i - 20 : i);   // phase order B,C,A,D
        int pn = 4 * g + wave;
        const u16* gp = w2s + (size_t)pn * 2048 + lane * 8;
        a[0] = *(const bf8*)(gp);
        a[1] = *(const bf8*)(gp + 512);
        a[2] = *(const bf8*)(gp + 1024);
        a[3] = *(const bf8*)(gp + 1536);
        bb = *(const float4*)(b2 + pn * 16 + q4 * 4);
    };
    loadA(0, a0, bb0);   // prefetch first tile under the whole prologue

    // phase 1: edge meta (+ deg histogram)
    if (tid < 64) {
        int ge = e0 + tid;
        int s = edge_index[ge];
        src_s[tid] = s;
        atomicAdd(&deg[s], 1);
        dst_s[tid] = edge_index[E_EDGES + ge];
        float4 sh = *(const float4*)(edge_sh + (size_t)ge * 4);
        sh0_s[tid] = sh.x; sh1_s[0][tid] = sh.y; sh1_s[1][tid] = sh.z; sh1_s[2][tid] = sh.w;
    }
    __syncthreads();

    // phase 2: node features (transposed into LDS) + ea tile bf16 into ovl.h
    {
        int e = tid >> 2, q = tid & 3;
        int dst = dst_s[e];
        const float* xp = node_attr + (size_t)dst * 112;
#pragma unroll
        for (int i = 0; i < 4; i++) {
            float4 f = *(const float4*)(xp + q * 16 + i * 4);
            int u = q * 16 + i * 4;
            sT[u + 0][e] = f.x; sT[u + 1][e] = f.y; sT[u + 2][e] = f.z; sT[u + 3][e] = f.w;
        }
        float vv[12];
#pragma unroll
        for (int i = 0; i < 3; i++) {
            float4 f = *(const float4*)(xp + 64 + q * 12 + i * 4);
            vv[i * 4 + 0] = f.x; vv[i * 4 + 1] = f.y; vv[i * 4 + 2] = f.z; vv[i * 4 + 3] = f.w;
        }
        float s1x = sh1_s[0][e], s1y = sh1_s[1][e], s1z = sh1_s[2][e];
#pragma unroll
        for (int u = 0; u < 4; u++) {
            float xa = vv[u * 3 + 0], xb = vv[u * 3 + 1], xc = vv[u * 3 + 2];
            int uu = q * 4 + u;
            vT[0][uu][e] = xa; vT[1][uu][e] = xb; vT[2][uu][e] = xc;
            pT[uu][e] = INV_SQRT3_CONST * (xa * s1x + xb * s1y + xc * s1z);
        }
        // ea staging: 32 cols per thread, f32 -> bf16
        const float4* src = (const float4*)(ea + (size_t)(e0 + e) * 128 + q * 32);
#pragma unroll
        for (int i = 0; i < 8; i++) {
            float4 f = src[i];
            int c = q * 32 + i * 4;
            ovl.h[e][c + 0] = f2bf(f.x); ovl.h[e][c + 1] = f2bf(f.y);
            ovl.h[e][c + 2] = f2bf(f.z); ovl.h[e][c + 3] = f2bf(f.w);
        }
    }
    __syncthreads();

    // phase 3: h = relu(ea@W1+b1) — 16-MFMA block (ea read from ovl.h, stride 136)
    {
        f4 hacc[4][2];
#pragma unroll
        for (int m = 0; m < 4; m++)
#pragma unroll
            for (int nt = 0; nt < 2; nt++) hacc[m][nt] = (f4){0.f, 0.f, 0.f, 0.f};
#pragma unroll
        for (int ks = 0; ks < 4; ks++) {
            bf8 a[4], bb[2];
#pragma unroll
            for (int m = 0; m < 4; m++) a[m] = *(const bf8*)&ovl.h[m * 16 + el][ks * 32 + q4 * 8];
#pragma unroll
            for (int nt = 0; nt < 2; nt++) {
                int n = wave * 32 + nt * 16 + el;
                bb[nt] = *(const bf8*)(w1t + n * 128 + ks * 32 + q4 * 8);
            }
#pragma unroll
            for (int m = 0; m < 4; m++)
#pragma unroll
                for (int nt = 0; nt < 2; nt++)
                    hacc[m][nt] = __builtin_amdgcn_mfma_f32_16x16x32_bf16(a[m], bb[nt], hacc[m][nt], 0, 0, 0);
        }
        __syncthreads();   // all ea reads done -> safe to overwrite ovl.h with h
#pragma unroll
        for (int m = 0; m < 4; m++)
#pragma unroll
            for (int nt = 0; nt < 2; nt++) {
                int n = wave * 32 + nt * 16 + el;
                float bias = b1[n];
#pragma unroll
                for (int r = 0; r < 4; r++) {
                    int e = m * 16 + q4 * 4 + r;
                    ovl.h[e][n] = f2bf(fmaxf(hacc[m][nt][r] + bias, 0.f));
                }
            }
    }
    __syncthreads();

    // h B-fragments for ALL 4 edge-groups (64 VGPRs) + per-lane sh0 factors
    bf8 hbf[4][4];
#pragma unroll
    for (int nt = 0; nt < 4; nt++)
#pragma unroll
        for (int ks = 0; ks < 4; ks++)
            hbf[nt][ks] = *(const bf8*)&ovl.h[nt * 16 + el][ks * 32 + q4 * 8];
    float sh0n4[4];
#pragma unroll
    for (int nt = 0; nt < 4; nt++) sh0n4[nt] = sh0_s[nt * 16 + el];
    __syncthreads();   // everyone done reading ovl.h -> becomes bc scratch

    // zero bc scratch (17408B = 4352 floats)
    for (int idx = tid; idx < 4352; idx += 256) ((float*)&ovl.bc)[idx] = 0.f;
    __syncthreads();   // bc zeroed before any wave's atomics

    auto mfmaG = [&](const bf8 (&a)[4], const float4& bb, f4 (&wf)[4]) {
#pragma unroll
        for (int nt = 0; nt < 4; nt++) wf[nt] = (f4){bb.x, bb.y, bb.z, bb.w};
#pragma unroll
        for (int ks = 0; ks < 4; ks++)
#pragma unroll
            for (int nt = 0; nt < 4; nt++)
                wf[nt] = __builtin_amdgcn_mfma_f32_16x16x32_bf16(a[ks], hbf[nt][ks], wf[nt], 0, 0, 0);
    };
    // result layout per lane: wf[nt][r] = w[edge = nt*16+el][col-in-tile = q4*4+r]

#define STEP(INXT, ACUR, BBCUR, ANXT, BBNXT, CON) \
    { if ((INXT) < 100) loadA((INXT), ANXT, BBNXT); mfmaG(ACUR, BBCUR, wf); CON; }

    f4 wf[4];

    // ---- B phase (i=0..15, g=64+i, u=4*i+wave; out col w = q4*4+r)
    {
        f4 accBn[4];
#pragma unroll
        for (int nt = 0; nt < 4; nt++) accBn[nt] = (f4){0.f, 0.f, 0.f, 0.f};
        auto conB = [&](int ib) {
            int u = 4 * ib + wave;
#pragma unroll
            for (int nt = 0; nt < 4; nt++) {
                float f = sT[u][nt * 16 + el];
                accBn[nt] += f * wf[nt];
            }
        };
        for (int ii = 0; ii < 16; ii += 2) {
            STEP(ii + 1, a0, bb0, a1, bb1, conB(ii));
            STEP(ii + 2, a1, bb1, a0, bb0, conB(ii + 1));
        }
#pragma unroll
        for (int nt = 0; nt < 4; nt++)
#pragma unroll
            for (int r = 0; r < 4; r++)
                atomicAdd(&ovl.bc.bcB[nt * 16 + el][q4 * 4 + r], accBn[nt][r]);
    }

    // ---- C phase (i=16..19, g=80+(i-16), u=4*(i-16)+wave)
    {
        f4 accCn[3][4];
#pragma unroll
        for (int i3 = 0; i3 < 3; i3++)
#pragma unroll
            for (int nt = 0; nt < 4; nt++) accCn[i3][nt] = (f4){0.f, 0.f, 0.f, 0.f};
        auto conC = [&](int ic) {
            int u = 4 * ic + wave;
#pragma unroll
            for (int nt = 0; nt < 4; nt++) {
#pragma unroll
                for (int i3 = 0; i3 < 3; i3++) {
                    float f = vT[i3][u][nt * 16 + el];
                    accCn[i3][nt] += f * wf[nt];
                }
            }
        };
        for (int ii = 0; ii < 4; ii += 2) {
            STEP(16 + ii + 1, a0, bb0, a1, bb1, conC(ii));
            STEP(16 + ii + 2, a1, bb1, a0, bb0, conC(ii + 1));
        }
#pragma unroll
        for (int i3 = 0; i3 < 3; i3++)
#pragma unroll
            for (int nt = 0; nt < 4; nt++)
#pragma unroll
                for (int r = 0; r < 4; r++)
                    atomicAdd(&ovl.bc.bcC[i3][nt * 16 + el][q4 * 4 + r], accCn[i3][nt][r]);
    }

    // ---- A phase (i=20..83, g=i-20=u) then D phase (i=84..99, u=i-84); both -> acc0n
    f4 acc0n[4];
#pragma unroll
    for (int nt = 0; nt < 4; nt++) acc0n[nt] = (f4){0.f, 0.f, 0.f, 0.f};
    {
        auto conA = [&](int ia) {
#pragma unroll
            for (int nt = 0; nt < 4; nt++) {
                float f = sh0n4[nt] * sT[ia][nt * 16 + el];
                acc0n[nt] += f * wf[nt];
            }
        };
        for (int ii = 0; ii < 64; ii += 2) {
            STEP(20 + ii + 1, a0, bb0, a1, bb1, conA(ii));
            STEP(20 + ii + 2, a1, bb1, a0, bb0, conA(ii + 1));
        }
        auto conD = [&](int id_) {
#pragma unroll
            for (int nt = 0; nt < 4; nt++) {
                float f = pT[id_][nt * 16 + el];
                acc0n[nt] += f * wf[nt];
            }
        };
        for (int ii = 0; ii < 16; ii += 2) {
            STEP(84 + ii + 1, a0, bb0, a1, bb1, conD(ii));
            STEP(84 + ii + 2, a1, bb1, a0, bb0, conD(ii + 1));
        }
    }
#undef STEP

    __syncthreads();   // loop reads of sT/vT/pT done; all bc atomics landed

    // out0 -> sT[e][c]: wave owns col block wave*16 (A/D cols), all 64 edges
#pragma unroll
    for (int nt = 0; nt < 4; nt++)
#pragma unroll
        for (int r = 0; r < 4; r++)
            sT[nt * 16 + el][wave * 16 + q4 * 4 + r] = N0_CONST * acc0n[nt][r];
    // out1 assembly from bc sums -> vflat [e*48 + w*3 + i]
    {
        float* vflat = (float*)vT;
        for (int idx = tid; idx < 3072; idx += 256) {
            int e = idx / 48;
            int rem = idx - e * 48;
            int w = rem / 3;
            int i3 = rem - w * 3;
            vflat[idx] = N0_CONST * (ovl.bc.bcB[e][w] * sh1_s[i3][e] + ovl.bc.bcC[i3][e][w] * sh0_s[e]);
        }
    }
    __syncthreads();

    // ATOMIC scatter of the 64x112 tile into out[src*112 + c] (device-scope, L2-resident 1.8MB)
    {
        const float* vflat = (const float*)vT;
        for (int idx = tid; idx < 64 * 112; idx += 256) {
            int e = idx / 112;
            int c = idx - e * 112;
            float val = (c < 64) ? sT[e][c] : vflat[e * 48 + (c - 64)];
            atomicAdd(&outsum[(size_t)src_s[e] * 112 + c], val);
        }
    }
}

// Final: out = out_sum/max(deg,1) + node_attr.
// ROUND-17: 448 blocks x 256 threads, one float4/thread (458752/4 = 114688 = 448*256 exactly;
// 112%4==0 so each float4 is within one node row: n = idx4/28). Replaces 4096x128 with 112
// active lanes (12.5% dead) + scalar loads; 9x fewer blocks, full lanes, 16B/lane.
__global__ __launch_bounds__(256) void k_fin(const int* __restrict__ deg,
                                             const float* __restrict__ node_attr,
                                             float* __restrict__ out) {
    int idx4 = blockIdx.x * 256 + threadIdx.x;     // [0, 114688)
    int n = idx4 / 28;
    float d = fmaxf((float)deg[n], 1.f);
    float inv = 1.f / d;
    float4 o = *(const float4*)(out + (size_t)idx4 * 4);
    float4 a = *(const float4*)(node_attr + (size_t)idx4 * 4);
    o.x = o.x * inv + a.x;
    o.y = o.y * inv + a.y;
    o.z = o.z * inv + a.z;
    o.w = o.w * inv + a.w;
    *(float4*)(out + (size_t)idx4 * 4) = o;
}

extern "C" void kernel_launch(void* const* d_in, const int* in_sizes, int n_in,
                              void* d_out, int out_size, void* d_ws, size_t ws_size,
                              hipStream_t stream) {
    const float* node_attr  = (const float*)d_in[0];
    const int*   edge_index = (const int*)d_in[1];
    const float* edge_attr  = (const float*)d_in[2];
    const float* edge_sh    = (const float*)d_in[3];
    const float* W1         = (const float*)d_in[6];
    const float* b1         = (const float*)d_in[7];
    const float* W2         = (const float*)d_in[8];
    const float* b2         = (const float*)d_in[9];
    float* out = (float*)d_out;

    char* ws = (char*)d_ws;
    u16*   w2s    = (u16*)ws;                     // 6400*128*2  = 1,638,400
    u16*   w1t    = (u16*)(ws + 1638400);         // 128*128*2   =    32,768
    int*   deg    = (int*)(ws + 1671168);         // 4096*4

    k_prep<<<457, 256, 0, stream>>>(W2, W1, w2s, w1t, deg, out);
    k_main<<<512, 256, 0, stream>>>(w2s, w1t, b1, edge_attr, b2, node_attr, edge_index, edge_sh, deg, out);
    k_fin<<<448, 256, 0, stream>>>(deg, node_attr, out);
}

// Round 18
// 180.429 us; speedup vs baseline: 2.2693x; 1.0074x over previous
//
#include <hip/hip_runtime.h>

typedef unsigned short u16;
typedef __bf16 bf8 __attribute__((ext_vector_type(8)));
typedef float f4 __attribute__((ext_vector_type(4)));

#define E_EDGES 32768
#define N_NODES 4096
// col layout of w (WNUM=6400): A[u<64][w<64] @0, B[u<64][w<16] @4096, C[u<16][w<16] @5120, D[u<16][w<64] @5376
// tile = 16 cols x 128 k = 4KB; group g covers tiles 4g..4g+3; A g<64, B 64..79, C 80..83, D 84..99
#define N0_CONST 0.1118033988749895f       // sqrt(1/80); also equals N1*INV_SQRT3
#define INV_SQRT3_CONST 0.5773502691896258f

__device__ __forceinline__ u16 f2bf(float f) {
    unsigned u = __float_as_uint(f);
    u += 0x7FFFu + ((u >> 16) & 1u);   // RNE
    return (u16)(u >> 16);
}

// Weight prep + zero-fill (R17 verbatim):
//  blocks 0..399:   w2s fragment-order swizzle (LDS re-stage, 32B-contiguous W2 reads)
//  blocks 400..415: w1t[c*128+k] = bf16(W1[k*128+c])
//  blocks 416..455: zero out[458752] floats (grid-stride)
//  block  456:      zero deg[4096]
__global__ __launch_bounds__(256) void k_prep(const float* __restrict__ W2, const float* __restrict__ W1,
                                              u16* __restrict__ w2s, u16* __restrict__ w1t,
                                              int* __restrict__ deg, float* __restrict__ outz) {
    int b = blockIdx.x;
    int tid = threadIdx.x;
    if (b < 400) {
        __shared__ float w2l[128][17];           // [k][c], +1 pad
        {
            int k = tid >> 1, c8 = (tid & 1) * 8;
            const float* src = W2 + (size_t)k * 6400 + b * 16 + c8;
            float tmpf[8];
#pragma unroll
            for (int j = 0; j < 8; j++) tmpf[j] = src[j];
#pragma unroll
            for (int j = 0; j < 8; j++) w2l[k][c8 + j] = tmpf[j];
        }
        __syncthreads();
        int ks = tid >> 6, l = tid & 63;
        int el = l & 15, q4 = l >> 4;
        u16 tmp[8];
#pragma unroll
        for (int j = 0; j < 8; j++)
            tmp[j] = f2bf(w2l[ks * 32 + q4 * 8 + j][el]);
        *(uint4*)(w2s + b * 2048 + ks * 512 + l * 8) = *(uint4*)tmp;
    } else if (b < 416) {
        int t = (b - 400) * 256 + tid;
#pragma unroll
        for (int i = 0; i < 4; i++) {
            int idx = t * 4 + i;                // idx = c*128 + k
            int c = idx >> 7, k = idx & 127;
            w1t[idx] = f2bf(W1[k * 128 + c]);
        }
    } else if (b < 456) {
        // zero out: 458752 floats = 114688 float4; 40 blocks x 256 threads grid-stride
        float4 z = {0.f, 0.f, 0.f, 0.f};
        for (int i4 = (b - 416) * 256 + tid; i4 < 114688; i4 += 40 * 256)
            *(float4*)(outz + (size_t)i4 * 4) = z;
    } else {
        *(int4*)&deg[tid * 16] = (int4){0, 0, 0, 0};
        *(int4*)&deg[tid * 16 + 4] = (int4){0, 0, 0, 0};
        *(int4*)&deg[tid * 16 + 8] = (int4){0, 0, 0, 0};
        *(int4*)&deg[tid * 16 + 12] = (int4){0, 0, 0, 0};
    }
}

// Fused: h = relu(ea@W1+b1) in-prologue -> w = h@W2+b2 tile-by-tile -> contraction
// -> ATOMIC scatter to out[src] (+ deg histogram). R17 structure; ROUND-18: T5 s_setprio(1)
// around the MFMA clusters. Mechanism: loop has NO barriers -> 8 waves/CU free-run at
// different phases (VMEM-issue vs MFMA vs LDS-contract) = the attn-like case where T5 gave
// +4-7% (m191), not the barrier-locked case where it was null (m190). Single-variable change.
__global__ __launch_bounds__(256, 2) void k_main(const u16* __restrict__ w2s,
                                                 const u16* __restrict__ w1t,
                                                 const float* __restrict__ b1,
                                                 const float* __restrict__ ea,
                                                 const float* __restrict__ b2,
                                                 const float* __restrict__ node_attr,
                                                 const int* __restrict__ edge_index,
                                                 const float* __restrict__ edge_sh,
                                                 int* __restrict__ deg,
                                                 float* __restrict__ outsum) {
    __shared__ alignas(16) union {
        u16 h[64][136];                               // 17408 B (prologue: ea staging, then h; +8 pad)
        struct { float bcB[64][17]; float bcC[3][64][17]; } bc;   // 17408 B (B/C cross-wave sums)
    } ovl;
    __shared__ float sT[64][66];              // s[u][e]; epilogue: out0[e][c]
    __shared__ float vT[3][16][66];           // v[i][u][e]; epilogue: out1 flat [e*48+cr]
    __shared__ float pT[16][66];              // INV_SQRT3*(v.sh1)[u][e]
    __shared__ float sh0_s[64];
    __shared__ float sh1_s[3][64];
    __shared__ int dst_s[64];
    __shared__ int src_s[64];

    int tid = threadIdx.x;
    int e0 = blockIdx.x * 64;
    int lane = tid & 63, wave = tid >> 6;
    int el = lane & 15, q4 = lane >> 4;

    // A-fragment double buffer + per-tile bias; issued earliest for latency
    bf8 a0[4], a1[4];
    float4 bb0, bb1;
    auto loadA = [&](int i, bf8 (&a)[4], float4& bb) {
        int g = (i < 20) ? 64 + i : (i < 84 ? i - 20 : i);   // phase order B,C,A,D
        int pn = 4 * g + wave;
        const u16* gp = w2s + (size_t)pn * 2048 + lane * 8;
        a[0] = *(const bf8*)(gp);
        a[1] = *(const bf8*)(gp + 512);
        a[2] = *(const bf8*)(gp + 1024);
        a[3] = *(const bf8*)(gp + 1536);
        bb = *(const float4*)(b2 + pn * 16 + q4 * 4);
    };
    loadA(0, a0, bb0);   // prefetch first tile under the whole prologue

    // phase 1: edge meta (+ deg histogram)
    if (tid < 64) {
        int ge = e0 + tid;
        int s = edge_index[ge];
        src_s[tid] = s;
        atomicAdd(&deg[s], 1);
        dst_s[tid] = edge_index[E_EDGES + ge];
        float4 sh = *(const float4*)(edge_sh + (size_t)ge * 4);
        sh0_s[tid] = sh.x; sh1_s[0][tid] = sh.y; sh1_s[1][tid] = sh.z; sh1_s[2][tid] = sh.w;
    }
    __syncthreads();

    // phase 2: node features (transposed into LDS) + ea tile bf16 into ovl.h
    {
        int e = tid >> 2, q = tid & 3;
        int dst = dst_s[e];
        const float* xp = node_attr + (size_t)dst * 112;
#pragma unroll
        for (int i = 0; i < 4; i++) {
            float4 f = *(const float4*)(xp + q * 16 + i * 4);
            int u = q * 16 + i * 4;
            sT[u + 0][e] = f.x; sT[u + 1][e] = f.y; sT[u + 2][e] = f.z; sT[u + 3][e] = f.w;
        }
        float vv[12];
#pragma unroll
        for (int i = 0; i < 3; i++) {
            float4 f = *(const float4*)(xp + 64 + q * 12 + i * 4);
            vv[i * 4 + 0] = f.x; vv[i * 4 + 1] = f.y; vv[i * 4 + 2] = f.z; vv[i * 4 + 3] = f.w;
        }
        float s1x = sh1_s[0][e], s1y = sh1_s[1][e], s1z = sh1_s[2][e];
#pragma unroll
        for (int u = 0; u < 4; u++) {
            float xa = vv[u * 3 + 0], xb = vv[u * 3 + 1], xc = vv[u * 3 + 2];
            int uu = q * 4 + u;
            vT[0][uu][e] = xa; vT[1][uu][e] = xb; vT[2][uu][e] = xc;
            pT[uu][e] = INV_SQRT3_CONST * (xa * s1x + xb * s1y + xc * s1z);
        }
        // ea staging: 32 cols per thread, f32 -> bf16
        const float4* src = (const float4*)(ea + (size_t)(e0 + e) * 128 + q * 32);
#pragma unroll
        for (int i = 0; i < 8; i++) {
            float4 f = src[i];
            int c = q * 32 + i * 4;
            ovl.h[e][c + 0] = f2bf(f.x); ovl.h[e][c + 1] = f2bf(f.y);
            ovl.h[e][c + 2] = f2bf(f.z); ovl.h[e][c + 3] = f2bf(f.w);
        }
    }
    __syncthreads();

    // phase 3: h = relu(ea@W1+b1) — 16-MFMA block (ea read from ovl.h, stride 136)
    {
        f4 hacc[4][2];
#pragma unroll
        for (int m = 0; m < 4; m++)
#pragma unroll
            for (int nt = 0; nt < 2; nt++) hacc[m][nt] = (f4){0.f, 0.f, 0.f, 0.f};
        __builtin_amdgcn_s_setprio(1);
#pragma unroll
        for (int ks = 0; ks < 4; ks++) {
            bf8 a[4], bb[2];
#pragma unroll
            for (int m = 0; m < 4; m++) a[m] = *(const bf8*)&ovl.h[m * 16 + el][ks * 32 + q4 * 8];
#pragma unroll
            for (int nt = 0; nt < 2; nt++) {
                int n = wave * 32 + nt * 16 + el;
                bb[nt] = *(const bf8*)(w1t + n * 128 + ks * 32 + q4 * 8);
            }
#pragma unroll
            for (int m = 0; m < 4; m++)
#pragma unroll
                for (int nt = 0; nt < 2; nt++)
                    hacc[m][nt] = __builtin_amdgcn_mfma_f32_16x16x32_bf16(a[m], bb[nt], hacc[m][nt], 0, 0, 0);
        }
        __builtin_amdgcn_s_setprio(0);
        __syncthreads();   // all ea reads done -> safe to overwrite ovl.h with h
#pragma unroll
        for (int m = 0; m < 4; m++)
#pragma unroll
            for (int nt = 0; nt < 2; nt++) {
                int n = wave * 32 + nt * 16 + el;
                float bias = b1[n];
#pragma unroll
                for (int r = 0; r < 4; r++) {
                    int e = m * 16 + q4 * 4 + r;
                    ovl.h[e][n] = f2bf(fmaxf(hacc[m][nt][r] + bias, 0.f));
                }
            }
    }
    __syncthreads();

    // h B-fragments for ALL 4 edge-groups (64 VGPRs) + per-lane sh0 factors
    bf8 hbf[4][4];
#pragma unroll
    for (int nt = 0; nt < 4; nt++)
#pragma unroll
        for (int ks = 0; ks < 4; ks++)
            hbf[nt][ks] = *(const bf8*)&ovl.h[nt * 16 + el][ks * 32 + q4 * 8];
    float sh0n4[4];
#pragma unroll
    for (int nt = 0; nt < 4; nt++) sh0n4[nt] = sh0_s[nt * 16 + el];
    __syncthreads();   // everyone done reading ovl.h -> becomes bc scratch

    // zero bc scratch (17408B = 4352 floats)
    for (int idx = tid; idx < 4352; idx += 256) ((float*)&ovl.bc)[idx] = 0.f;
    __syncthreads();   // bc zeroed before any wave's atomics

    auto mfmaG = [&](const bf8 (&a)[4], const float4& bb, f4 (&wf)[4]) {
#pragma unroll
        for (int nt = 0; nt < 4; nt++) wf[nt] = (f4){bb.x, bb.y, bb.z, bb.w};
        __builtin_amdgcn_s_setprio(1);
#pragma unroll
        for (int ks = 0; ks < 4; ks++)
#pragma unroll
            for (int nt = 0; nt < 4; nt++)
                wf[nt] = __builtin_amdgcn_mfma_f32_16x16x32_bf16(a[ks], hbf[nt][ks], wf[nt], 0, 0, 0);
        __builtin_amdgcn_s_setprio(0);
    };
    // result layout per lane: wf[nt][r] = w[edge = nt*16+el][col-in-tile = q4*4+r]

#define STEP(INXT, ACUR, BBCUR, ANXT, BBNXT, CON) \
    { if ((INXT) < 100) loadA((INXT), ANXT, BBNXT); mfmaG(ACUR, BBCUR, wf); CON; }

    f4 wf[4];

    // ---- B phase (i=0..15, g=64+i, u=4*i+wave; out col w = q4*4+r)
    {
        f4 accBn[4];
#pragma unroll
        for (int nt = 0; nt < 4; nt++) accBn[nt] = (f4){0.f, 0.f, 0.f, 0.f};
        auto conB = [&](int ib) {
            int u = 4 * ib + wave;
#pragma unroll
            for (int nt = 0; nt < 4; nt++) {
                float f = sT[u][nt * 16 + el];
                accBn[nt] += f * wf[nt];
            }
        };
        for (int ii = 0; ii < 16; ii += 2) {
            STEP(ii + 1, a0, bb0, a1, bb1, conB(ii));
            STEP(ii + 2, a1, bb1, a0, bb0, conB(ii + 1));
        }
#pragma unroll
        for (int nt = 0; nt < 4; nt++)
#pragma unroll
            for (int r = 0; r < 4; r++)
                atomicAdd(&ovl.bc.bcB[nt * 16 + el][q4 * 4 + r], accBn[nt][r]);
    }

    // ---- C phase (i=16..19, g=80+(i-16), u=4*(i-16)+wave)
    {
        f4 accCn[3][4];
#pragma unroll
        for (int i3 = 0; i3 < 3; i3++)
#pragma unroll
            for (int nt = 0; nt < 4; nt++) accCn[i3][nt] = (f4){0.f, 0.f, 0.f, 0.f};
        auto conC = [&](int ic) {
            int u = 4 * ic + wave;
#pragma unroll
            for (int nt = 0; nt < 4; nt++) {
#pragma unroll
                for (int i3 = 0; i3 < 3; i3++) {
                    float f = vT[i3][u][nt * 16 + el];
                    accCn[i3][nt] += f * wf[nt];
                }
            }
        };
        for (int ii = 0; ii < 4; ii += 2) {
            STEP(16 + ii + 1, a0, bb0, a1, bb1, conC(ii));
            STEP(16 + ii + 2, a1, bb1, a0, bb0, conC(ii + 1));
        }
#pragma unroll
        for (int i3 = 0; i3 < 3; i3++)
#pragma unroll
            for (int nt = 0; nt < 4; nt++)
#pragma unroll
                for (int r = 0; r < 4; r++)
                    atomicAdd(&ovl.bc.bcC[i3][nt * 16 + el][q4 * 4 + r], accCn[i3][nt][r]);
    }

    // ---- A phase (i=20..83, g=i-20=u) then D phase (i=84..99, u=i-84); both -> acc0n
    f4 acc0n[4];
#pragma unroll
    for (int nt = 0; nt < 4; nt++) acc0n[nt] = (f4){0.f, 0.f, 0.f, 0.f};
    {
        auto conA = [&](int ia) {
#pragma unroll
            for (int nt = 0; nt < 4; nt++) {
                float f = sh0n4[nt] * sT[ia][nt * 16 + el];
                acc0n[nt] += f * wf[nt];
            }
        };
        for (int ii = 0; ii < 64; ii += 2) {
            STEP(20 + ii + 1, a0, bb0, a1, bb1, conA(ii));
            STEP(20 + ii + 2, a1, bb1, a0, bb0, conA(ii + 1));
        }
        auto conD = [&](int id_) {
#pragma unroll
            for (int nt = 0; nt < 4; nt++) {
                float f = pT[id_][nt * 16 + el];
                acc0n[nt] += f * wf[nt];
            }
        };
        for (int ii = 0; ii < 16; ii += 2) {
            STEP(84 + ii + 1, a0, bb0, a1, bb1, conD(ii));
            STEP(84 + ii + 2, a1, bb1, a0, bb0, conD(ii + 1));
        }
    }
#undef STEP

    __syncthreads();   // loop reads of sT/vT/pT done; all bc atomics landed

    // out0 -> sT[e][c]: wave owns col block wave*16 (A/D cols), all 64 edges
#pragma unroll
    for (int nt = 0; nt < 4; nt++)
#pragma unroll
        for (int r = 0; r < 4; r++)
            sT[nt * 16 + el][wave * 16 + q4 * 4 + r] = N0_CONST * acc0n[nt][r];
    // out1 assembly from bc sums -> vflat [e*48 + w*3 + i]
    {
        float* vflat = (float*)vT;
        for (int idx = tid; idx < 3072; idx += 256) {
            int e = idx / 48;
            int rem = idx - e * 48;
            int w = rem / 3;
            int i3 = rem - w * 3;
            vflat[idx] = N0_CONST * (ovl.bc.bcB[e][w] * sh1_s[i3][e] + ovl.bc.bcC[i3][e][w] * sh0_s[e]);
        }
    }
    __syncthreads();

    // ATOMIC scatter of the 64x112 tile into out[src*112 + c] (device-scope, L2-resident 1.8MB)
    {
        const float* vflat = (const float*)vT;
        for (int idx = tid; idx < 64 * 112; idx += 256) {
            int e = idx / 112;
            int c = idx - e * 112;
            float val = (c < 64) ? sT[e][c] : vflat[e * 48 + (c - 64)];
            atomicAdd(&outsum[(size_t)src_s[e] * 112 + c], val);
        }
    }
}

// Final: out = out_sum/max(deg,1) + node_attr. (R17 verbatim: 448x256, one float4/thread)
__global__ __launch_bounds__(256) void k_fin(const int* __restrict__ deg,
                                             const float* __restrict__ node_attr,
                                             float* __restrict__ out) {
    int idx4 = blockIdx.x * 256 + threadIdx.x;     // [0, 114688)
    int n = idx4 / 28;
    float d = fmaxf((float)deg[n], 1.f);
    float inv = 1.f / d;
    float4 o = *(const float4*)(out + (size_t)idx4 * 4);
    float4 a = *(const float4*)(node_attr + (size_t)idx4 * 4);
    o.x = o.x * inv + a.x;
    o.y = o.y * inv + a.y;
    o.z = o.z * inv + a.z;
    o.w = o.w * inv + a.w;
    *(float4*)(out + (size_t)idx4 * 4) = o;
}

extern "C" void kernel_launch(void* const* d_in, const int* in_sizes, int n_in,
                              void* d_out, int out_size, void* d_ws, size_t ws_size,
                              hipStream_t stream) {
    const float* node_attr  = (const float*)d_in[0];
    const int*   edge_index = (const int*)d_in[1];
    const float* edge_attr  = (const float*)d_in[2];
    const float* edge_sh    = (const float*)d_in[3];
    const float* W1         = (const float*)d_in[6];
    const float* b1         = (const float*)d_in[7];
    const float* W2         = (const float*)d_in[8];
    const float* b2         = (const float*)d_in[9];
    float* out = (float*)d_out;

    char* ws = (char*)d_ws;
    u16*   w2s    = (u16*)ws;                     // 6400*128*2  = 1,638,400
    u16*   w1t    = (u16*)(ws + 1638400);         // 128*128*2   =    32,768
    int*   deg    = (int*)(ws + 1671168);         // 4096*4

    k_prep<<<457, 256, 0, stream>>>(W2, W1, w2s, w1t, deg, out);
    k_main<<<512, 256, 0, stream>>>(w2s, w1t, b1, edge_attr, b2, node_attr, edge_index, edge_sh, deg, out);
    k_fin<<<448, 256, 0, stream>>>(deg, node_attr, out);
}